// Round 1
// baseline (264.644 us; speedup 1.0000x reference)
//
#include <hip/hip_runtime.h>
#include <math.h>

// Problem constants
// B=32, HID=4096, NH=32, NKV=8, HS=128, BS=16, MAXS=2048, groups=4

// ---------------------------------------------------------------------------
// Split-K f32 GEMM body: out[b][n] += x[b][:] . w[n][:] over K-chunk of 256.
// BM=32 (all batches), BN=256 rows, BK=32. 256 threads.
// Thread t: nsub=t&31 handles n = nsub+32*jn (jn<8); bsub=t>>5 handles
// b = bsub*4+jb (jb<4). 32 accumulators.
// LDS: x staged [b][k] (reads are wave-broadcast), w transposed [k][n] with
// +1 pad so stride-32 n reads hit all 32 banks.
// ---------------------------------------------------------------------------
__device__ __forceinline__ void gemm_body(
    const float* __restrict__ x,   // [32][4096]
    const float* __restrict__ w,   // row-major, rows of 4096, offset to tile
    float* __restrict__ dst,       // + b*dstride + n  (atomicAdd)
    int dstride, int kbase)
{
    __shared__ float xs[32][36];
    __shared__ float wsm[32][257];   // [k][n]
    int t = threadIdx.x;
    float acc[4][8];
#pragma unroll
    for (int i = 0; i < 4; ++i)
#pragma unroll
        for (int j = 0; j < 8; ++j) acc[i][j] = 0.f;

    int nsub = t & 31, bsub = t >> 5;

    for (int kt = 0; kt < 256; kt += 32) {
        int k0 = kbase + kt;
        // stage x tile
        {
            int b = t >> 3, k4 = (t & 7) << 2;
            float4 xv = *(const float4*)(x + (size_t)b * 4096 + k0 + k4);
            *(float4*)&xs[b][k4] = xv;
        }
        // stage w tile (transpose to [k][n])
        {
            int k4 = (t & 7) << 2;
            int nl0 = t >> 3;
#pragma unroll
            for (int i = 0; i < 8; ++i) {
                int nl = nl0 + (i << 5);
                float4 wv = *(const float4*)(w + (size_t)nl * 4096 + k0 + k4);
                wsm[k4 + 0][nl] = wv.x;
                wsm[k4 + 1][nl] = wv.y;
                wsm[k4 + 2][nl] = wv.z;
                wsm[k4 + 3][nl] = wv.w;
            }
        }
        __syncthreads();
#pragma unroll
        for (int k = 0; k < 32; ++k) {
            float xv[4], wv[8];
#pragma unroll
            for (int j = 0; j < 4; ++j) xv[j] = xs[bsub * 4 + j][k];
#pragma unroll
            for (int j = 0; j < 8; ++j) wv[j] = wsm[k][nsub + (j << 5)];
#pragma unroll
            for (int jb = 0; jb < 4; ++jb)
#pragma unroll
                for (int jn = 0; jn < 8; ++jn)
                    acc[jb][jn] = fmaf(xv[jb], wv[jn], acc[jb][jn]);
        }
        __syncthreads();
    }
#pragma unroll
    for (int jb = 0; jb < 4; ++jb) {
        int b = bsub * 4 + jb;
#pragma unroll
        for (int jn = 0; jn < 8; ++jn)
            atomicAdd(dst + (size_t)b * dstride + nsub + (jn << 5), acc[jb][jn]);
    }
}

// grid = 24 tiles * 16 splits = 384. Tiles 0..15 -> wq, 16..19 -> wk, 20..23 -> wv.
__global__ __launch_bounds__(256) void qkv_gemm(
    const float* __restrict__ x, const float* __restrict__ wq,
    const float* __restrict__ wk, const float* __restrict__ wv,
    float* __restrict__ qb, float* __restrict__ knb, float* __restrict__ vnb)
{
    int split = blockIdx.x & 15;
    int tile  = blockIdx.x >> 4;
    const float* w; float* dst; int dstride;
    if (tile < 16)      { w = wq + (size_t)tile * 256 * 4096;        dst = qb  + tile * 256;        dstride = 4096; }
    else if (tile < 20) { w = wk + (size_t)(tile - 16) * 256 * 4096; dst = knb + (tile - 16) * 256; dstride = 1024; }
    else                { w = wv + (size_t)(tile - 20) * 256 * 4096; dst = vnb + (tile - 20) * 256; dstride = 1024; }
    gemm_body(x, w, dst, dstride, split * 256);
}

// grid = 16 tiles * 16 splits = 256
__global__ __launch_bounds__(256) void wo_gemm(
    const float* __restrict__ attn, const float* __restrict__ wo,
    float* __restrict__ out)
{
    int split = blockIdx.x & 15;
    int tile  = blockIdx.x >> 4;
    gemm_body(attn, wo + (size_t)tile * 256 * 4096, out + tile * 256, 4096, split * 256);
}

// ---------------------------------------------------------------------------
// RoPE in-place on q (32 heads) and k_new (8 heads). grid = 32*40, block = 64.
// Thread d<64 rotates the pair (d, d+64).
// ---------------------------------------------------------------------------
__global__ void rope_kernel(float* __restrict__ qb, float* __restrict__ knb,
                            const int* __restrict__ lens)
{
    int bid = blockIdx.x;
    int b = bid / 40, r = bid % 40;
    float* row = (r < 32) ? (qb + (size_t)b * 4096 + r * 128)
                          : (knb + (size_t)b * 1024 + (r - 32) * 128);
    int d = threadIdx.x;
    float pos = (float)(lens[b] - 1);
    // inv_freq = 10000^(-d/64) = 2^(-d * log2(10000)/64)
    float inv = exp2f(-(float)d * 0.20762050595016273f);
    float fr = pos * inv;
    float s, c;
    sincosf(fr, &s, &c);
    float x1 = row[d], x2 = row[d + 64];
    row[d]      = x1 * c - x2 * s;
    row[d + 64] = x2 * c + x1 * s;
}

// ---------------------------------------------------------------------------
// Flash-decode attention chunk kernel.
// grid = B*NKV*NCHUNK = 32*8*8 = 2048, block = 256 (4 waves = 4 GQA groups).
// Each block: chunk of 256 positions, tiles of 64. K tile staged into LDS with
// XOR-swizzled f4 columns (lane-per-row reads conflict-free); V staged into the
// SAME buffer after scores. Online softmax per wave. Position len-1 sources
// the new (RoPE'd) k/v instead of the cache.
// Partials per (b,h,chunk,g): [m, l, O[128]] = 130 floats.
// ---------------------------------------------------------------------------
__global__ __launch_bounds__(256) void attn_kernel(
    const float* __restrict__ kc, const float* __restrict__ vc,
    const float* __restrict__ qb, const float* __restrict__ knb,
    const float* __restrict__ vnb,
    const int* __restrict__ btab, const int* __restrict__ lens,
    float* __restrict__ part)
{
    int bid = blockIdx.x;
    int c = bid & 7, h = (bid >> 3) & 7, b = bid >> 6;
    int len = lens[b];
    int p0 = c << 8;
    if (p0 >= len) return;
    int pend = min(len - p0, 256);
    int last = len - 1;

    __shared__ float ks[64][128];
    __shared__ float qs[4][128];
    __shared__ float ps[4][64];

    int t = threadIdx.x;
    int wave = t >> 6, lane = t & 63;

    if (t < 128) {
        int g = t >> 5, d4 = (t & 31) << 2;
        *(float4*)&qs[g][d4] =
            *(const float4*)(qb + (size_t)b * 4096 + (size_t)(h * 4 + g) * 128 + d4);
    }

    float m = -INFINITY, l = 0.f, o0 = 0.f, o1 = 0.f;
    const float scale = 0.08838834764831845f;  // 1/sqrt(128)
    int xm = lane & 7;
    int f4 = t & 31;
    int prow = t >> 5;

    for (int pt = 0; pt < pend; pt += 64) {
        int tlen = min(pend - pt, 64);
        // ---- stage K (swizzled cols) ----
#pragma unroll
        for (int pass = 0; pass < 8; ++pass) {
            int pl = (pass << 3) + prow;
            if (pl < tlen) {
                int p = p0 + pt + pl;
                const float* src;
                if (p == last) src = knb + ((size_t)b * 8 + h) * 128;
                else {
                    int slot = btab[b * 128 + (p >> 4)] * 16 + (p & 15);
                    src = kc + (size_t)slot * 1024 + (size_t)h * 128;
                }
                int col = f4 ^ (pl & 7);
                *(float4*)&ks[pl][col << 2] = *(const float4*)(src + (f4 << 2));
            }
        }
        __syncthreads();
        // ---- scores: lane = position row ----
        float s = -INFINITY;
        if (lane < tlen) {
            float acc = 0.f;
#pragma unroll
            for (int cc = 0; cc < 32; ++cc) {
                float4 kv = *(float4*)&ks[lane][(cc ^ xm) << 2];
                float4 qv = *(float4*)&qs[wave][cc << 2];
                acc = fmaf(kv.x, qv.x, acc);
                acc = fmaf(kv.y, qv.y, acc);
                acc = fmaf(kv.z, qv.z, acc);
                acc = fmaf(kv.w, qv.w, acc);
            }
            s = acc * scale;
        }
        float smax = s;
#pragma unroll
        for (int off = 32; off; off >>= 1) smax = fmaxf(smax, __shfl_xor(smax, off, 64));
        float mnew = fmaxf(m, smax);
        float corr = __expf(m - mnew);           // first tile: exp(-inf)=0
        float pexp = (lane < tlen) ? __expf(s - mnew) : 0.f;
        float psum = pexp;
#pragma unroll
        for (int off = 32; off; off >>= 1) psum += __shfl_xor(psum, off, 64);
        l = l * corr + psum;
        m = mnew;
        o0 *= corr; o1 *= corr;
        ps[wave][lane] = pexp;
        __syncthreads();
        // ---- stage V (plain) into same buffer ----
#pragma unroll
        for (int pass = 0; pass < 8; ++pass) {
            int pl = (pass << 3) + prow;
            if (pl < tlen) {
                int p = p0 + pt + pl;
                const float* src;
                if (p == last) src = vnb + ((size_t)b * 8 + h) * 128;
                else {
                    int slot = btab[b * 128 + (p >> 4)] * 16 + (p & 15);
                    src = vc + (size_t)slot * 1024 + (size_t)h * 128;
                }
                *(float4*)&ks[pl][f4 << 2] = *(const float4*)(src + (f4 << 2));
            }
        }
        __syncthreads();
        // ---- PV: lane owns d = 2*lane, 2*lane+1 (2-way bank alias = free) ----
        {
            int d0 = lane << 1;
            for (int p = 0; p < tlen; ++p) {
                float pw = ps[wave][p];
                float2 vv = *(float2*)&ks[p][d0];
                o0 = fmaf(pw, vv.x, o0);
                o1 = fmaf(pw, vv.y, o1);
            }
        }
        __syncthreads();
    }
    // write partial (m, l, O[128])
    float* pg = part + ((size_t)(((b * 8 + h) * 8 + c) * 4 + wave)) * 130;
    if (lane == 0) { pg[0] = m; pg[1] = l; }
    pg[2 + (lane << 1)] = o0;
    pg[3 + (lane << 1)] = o1;
}

// grid = 256 (b*8+h), block = 256 (4 groups x 64 lanes)
__global__ __launch_bounds__(256) void combine_kernel(
    const float* __restrict__ part, const int* __restrict__ lens,
    float* __restrict__ attn)
{
    int b = blockIdx.x >> 3, h = blockIdx.x & 7;
    int t = threadIdx.x;
    int g = t >> 6, lane = t & 63;
    int len = lens[b];
    int nch = (len + 255) >> 8;
    size_t base = ((size_t)(b * 8 + h) * 32 + g) * 130;  // chunk stride = 4*130
    float M = -INFINITY;
    for (int cc = 0; cc < nch; ++cc)
        M = fmaxf(M, part[base + (size_t)cc * 520]);
    float denom = 0.f, a0 = 0.f, a1 = 0.f;
    for (int cc = 0; cc < nch; ++cc) {
        const float* pg = part + base + (size_t)cc * 520;
        float w = __expf(pg[0] - M);
        denom += w * pg[1];
        a0 += w * pg[2 + (lane << 1)];
        a1 += w * pg[3 + (lane << 1)];
    }
    float inv = 1.f / denom;
    float* dst = attn + (size_t)b * 4096 + (size_t)(h * 4 + g) * 128 + (lane << 1);
    dst[0] = a0 * inv;
    dst[1] = a1 * inv;
}

// ---------------------------------------------------------------------------
// Workspace layout (floats):
//  qb   [32][4096]          @ 0
//  knb  [32][8][128]        @ 131072
//  vnb  [32][8][128]        @ 163840
//  attn [32][4096]          @ 196608
//  part [32][8][8][4][130]  @ 327680    (1,064,960 floats)
// total ~5.6 MB
// ---------------------------------------------------------------------------
extern "C" void kernel_launch(void* const* d_in, const int* in_sizes, int n_in,
                              void* d_out, int out_size, void* d_ws, size_t ws_size,
                              hipStream_t stream)
{
    const float* x   = (const float*)d_in[0];
    const float* wq  = (const float*)d_in[1];
    const float* wk  = (const float*)d_in[2];
    const float* wv  = (const float*)d_in[3];
    const float* wo  = (const float*)d_in[4];
    const float* kc  = (const float*)d_in[5];
    const float* vc  = (const float*)d_in[6];
    const int* btab  = (const int*)d_in[8];
    const int* lens  = (const int*)d_in[10];

    float* qb   = (float*)d_ws;
    float* knb  = qb  + 32 * 4096;
    float* vnb  = knb + 32 * 1024;
    float* attn = vnb + 32 * 1024;
    float* part = attn + 32 * 4096;
    float* outp = (float*)d_out;

    // zero the atomic-accumulation targets
    hipMemsetAsync(d_ws, 0, (size_t)(32 * 4096 + 2 * 32 * 1024) * sizeof(float), stream);
    hipMemsetAsync(d_out, 0, (size_t)32 * 4096 * sizeof(float), stream);

    qkv_gemm<<<384, 256, 0, stream>>>(x, wq, wk, wv, qb, knb, vnb);
    rope_kernel<<<32 * 40, 64, 0, stream>>>(qb, knb, lens);
    attn_kernel<<<2048, 256, 0, stream>>>(kc, vc, qb, knb, vnb, btab, lens, part);
    combine_kernel<<<256, 256, 0, stream>>>(part, lens, attn);
    wo_gemm<<<256, 256, 0, stream>>>(attn, wo, outp);
}